// Round 7
// baseline (1305.430 us; speedup 1.0000x reference)
//
#include <hip/hip_runtime.h>
#include <hip/hip_bf16.h>

// BERT stack: L=12(+1 dup of layer0), H=12, E=768, D=64, B=4, S=512 -> BS=2048 tokens.
// Faithful bugs preserved:
//  - attention flattens batch: 2048 tokens attend to each other globally, q==k==v
//  - zc = z.reshape(768,2048) is a FLAT VIEW of z[H][N][D]  (no transpose)
//  - mh = (wo@zc).reshape(B,S,E) is a FLAT VIEW of mh_mat[768][2048]
//  - pe: p = 10000 for e<384 else 10001; even e -> sin, odd -> cos; s = t % 512
// Inputs/outputs fp32. All GEMMs + attention bf16 MFMA (fp32 accumulate);
// residual/LN chain fp32. Weights pre-converted to bf16 once per launch.
// Attention: no-max softmax => additive partials, ksplit=4.
// gemm_out/ffn: 128x64 tiles (wave=32x64, B-frag reuse), ksplit=2; the
// partial sum is folded into the LN kernel (reads both partials).
// ws_size ~256MB (measured via harness poison fill) -> layout fits easily.

#define BS_TOK 2048
#define EMB 768
#define NH 12
#define HD 64
#define WQN (12 * NH * EMB * HD)  // elems per weight stack (7077888)

typedef __attribute__((ext_vector_type(8))) short bf16x8;
typedef __attribute__((ext_vector_type(4))) float f32x4;

__device__ __forceinline__ short f2bf(float f) {
  union { float f; unsigned u; } v;
  v.f = f;
  unsigned r = (v.u + 0x7FFF + ((v.u >> 16) & 1)) >> 16;  // RNE
  return (short)(unsigned short)r;
}

#define MFMA16(a, b, c) __builtin_amdgcn_mfma_f32_16x16x32_bf16(a, b, c, 0, 0, 0)
// XOR-swizzled LDS address for [r][k] tiles, 64-elem rows (zero-conflict, validated r3-r6)
#define SW64(r, k) ((r) * 64 + ((((k) >> 3) ^ ((r) & 7)) << 3) + ((k) & 7))

// ---------------------------------------------------------------- weight prep
// y=0: wo -> wob ; y=1: fw -> fwb
__global__ __launch_bounds__(256) void cvt_weights_kernel(const float* __restrict__ wo,
                                                          const float* __restrict__ fw,
                                                          short* __restrict__ wob,
                                                          short* __restrict__ fwb) {
  const float* src = blockIdx.y ? fw : wo;
  short* dst = blockIdx.y ? fwb : wob;
  int i = (blockIdx.x * 256 + threadIdx.x) * 8;
  float4 a = *(const float4*)(src + i);
  float4 b = *(const float4*)(src + i + 4);
  bf16x8 t;
  t[0] = f2bf(a.x); t[1] = f2bf(a.y); t[2] = f2bf(a.z); t[3] = f2bf(a.w);
  t[4] = f2bf(b.x); t[5] = f2bf(b.y); t[6] = f2bf(b.z); t[7] = f2bf(b.w);
  *(bf16x8*)(dst + i) = t;
}

// wqT[l][h][d][e] <- wq[l][h][e][d], bf16
__global__ __launch_bounds__(256) void wq_trans_kernel(const float* __restrict__ wq,
                                                       short* __restrict__ wqT) {
  __shared__ short T[64 * 64];
  const int et = blockIdx.x;  // e-tile (12)
  const int lh = blockIdx.y;  // l*NH+h (144)
  const int tid = threadIdx.x;
  const float* src = wq + ((size_t)lh * EMB + et * 64) * HD;
  {
    int r = tid >> 2, c16 = (tid & 3) << 4;
    const float* p = src + r * HD + c16;
    float4 x0 = *(const float4*)(p + 0);
    float4 x1 = *(const float4*)(p + 4);
    float4 x2 = *(const float4*)(p + 8);
    float4 x3 = *(const float4*)(p + 12);
    bf16x8 a, b;
    a[0] = f2bf(x0.x); a[1] = f2bf(x0.y); a[2] = f2bf(x0.z); a[3] = f2bf(x0.w);
    a[4] = f2bf(x1.x); a[5] = f2bf(x1.y); a[6] = f2bf(x1.z); a[7] = f2bf(x1.w);
    b[0] = f2bf(x2.x); b[1] = f2bf(x2.y); b[2] = f2bf(x2.z); b[3] = f2bf(x2.w);
    b[4] = f2bf(x3.x); b[5] = f2bf(x3.y); b[6] = f2bf(x3.z); b[7] = f2bf(x3.w);
    int g = c16 >> 3;
    *(bf16x8*)&T[r * 64 + ((g ^ (r & 7)) << 3)] = a;
    *(bf16x8*)&T[r * 64 + (((g + 1) ^ (r & 7)) << 3)] = b;
  }
  __syncthreads();
  {
    int d = tid >> 2, e16 = (tid & 3) << 4;
    bf16x8 t0, t1;
#pragma unroll
    for (int j = 0; j < 8; ++j) t0[j] = T[SW64(e16 + j, d)];
#pragma unroll
    for (int j = 0; j < 8; ++j) t1[j] = T[SW64(e16 + 8 + j, d)];
    short* q = wqT + ((size_t)lh * HD + d) * EMB + et * 64 + e16;
    *(bf16x8*)(q) = t0;
    *(bf16x8*)(q + 8) = t1;
  }
}

// ---------------------------------------------------------------- pe + tokens
__global__ __launch_bounds__(256) void pe_add_kernel(const float* __restrict__ tok,
                                                     float* __restrict__ X,
                                                     short* __restrict__ Xb) {
  int idx = blockIdx.x * 256 + threadIdx.x;   // < 2048*768
  int e = idx % EMB;
  int t = idx / EMB;
  int s = t & 511;                            // t = b*512 + s
  float p = (e < 384) ? 10000.0f : 10001.0f;  // 10000 XOR ((2e)//768)
  float ang = (float)s / p;
  float pe = (e & 1) ? cosf(ang) : sinf(ang);
  float v = tok[idx] + pe;
  X[idx] = v;
  Xb[idx] = f2bf(v);
}

// ---------------- staging helpers ----
// 64 rows x 64 k, 256 threads: dst[r][k] <- bf16 src[row0+r][k0+k] (k contig)
__device__ __forceinline__ void stage_direct_bf16(const short* __restrict__ src, int ld,
                                                  int row0, int k0, short* dst, int tid) {
  int r = tid >> 2, kb = (tid & 3) << 4;
  const short* p = src + (size_t)(row0 + r) * ld + k0 + kb;
  bf16x8 x0 = *(const bf16x8*)(p);
  bf16x8 x1 = *(const bf16x8*)(p + 8);
  int g = kb >> 3;
  *(bf16x8*)&dst[r * 64 + ((g ^ (r & 7)) << 3)] = x0;
  *(bf16x8*)&dst[r * 64 + (((g + 1) ^ (r & 7)) << 3)] = x1;
}

// 128 rows x 64 k, 256 threads
__device__ __forceinline__ void stage_direct128(const short* __restrict__ src, int ld,
                                                int row0, int k0, short* dst, int tid) {
  int r = tid >> 1, kb = (tid & 1) << 5;
  const short* p = src + (size_t)(row0 + r) * ld + k0 + kb;
  bf16x8 x0 = *(const bf16x8*)(p);
  bf16x8 x1 = *(const bf16x8*)(p + 8);
  bf16x8 x2 = *(const bf16x8*)(p + 16);
  bf16x8 x3 = *(const bf16x8*)(p + 24);
  int g = kb >> 3;
  *(bf16x8*)&dst[r * 64 + (((g + 0) ^ (r & 7)) << 3)] = x0;
  *(bf16x8*)&dst[r * 64 + (((g + 1) ^ (r & 7)) << 3)] = x1;
  *(bf16x8*)&dst[r * 64 + (((g + 2) ^ (r & 7)) << 3)] = x2;
  *(bf16x8*)&dst[r * 64 + (((g + 3) ^ (r & 7)) << 3)] = x3;
}

// transpose: dst[n][k] <- bf16 src[k0+k][col0+n] (n contig in src)
__device__ __forceinline__ void stage_trans_bf16(const short* __restrict__ src, int ld,
                                                 int k0, int col0, short* dst, int tid) {
  int kk = tid >> 2, nb = (tid & 3) << 4;
  const short* p = src + (size_t)(k0 + kk) * ld + col0 + nb;
  bf16x8 x0 = *(const bf16x8*)(p + 0);
  bf16x8 x1 = *(const bf16x8*)(p + 8);
#pragma unroll
  for (int j = 0; j < 8; ++j) dst[SW64(nb + j, kk)] = x0[j];
#pragma unroll
  for (int j = 0; j < 8; ++j) dst[SW64(nb + 8 + j, kk)] = x1[j];
}

// wave computes 16 rows x 64 cols (64x64 block tile, 4 waves)
#define GEMM_TILE_COMPUTE(As, Bs, acc)                                              \
  {                                                                                 \
    _Pragma("unroll") for (int s = 0; s < 2; ++s) {                                 \
      int ra = (w << 4) + l15;                                                      \
      bf16x8 af = *(const bf16x8*)&As[ra * 64 + ((((s << 2) + quad) ^ (ra & 7)) << 3)]; \
      _Pragma("unroll") for (int nt = 0; nt < 4; ++nt) {                            \
        int rb = (nt << 4) + l15;                                                   \
        bf16x8 bf = *(const bf16x8*)&Bs[rb * 64 + ((((s << 2) + quad) ^ (rb & 7)) << 3)]; \
        acc[nt] = MFMA16(af, bf, acc[nt]);                                          \
      }                                                                             \
    }                                                                               \
  }

// wave computes 32 rows x 64 cols (128x64 block tile, 4 waves); B-frag reused 2x
#define GEMM_TILE_COMPUTE2(As, Bs, acc)                                             \
  {                                                                                 \
    _Pragma("unroll") for (int s = 0; s < 2; ++s) {                                 \
      bf16x8 af[2];                                                                 \
      _Pragma("unroll") for (int u = 0; u < 2; ++u) {                               \
        int ra = (w << 5) + (u << 4) + l15;                                         \
        af[u] = *(const bf16x8*)&As[ra * 64 + ((((s << 2) + quad) ^ (ra & 7)) << 3)]; \
      }                                                                             \
      _Pragma("unroll") for (int nt = 0; nt < 4; ++nt) {                            \
        int rb = (nt << 4) + l15;                                                   \
        bf16x8 bf = *(const bf16x8*)&Bs[rb * 64 + ((((s << 2) + quad) ^ (rb & 7)) << 3)]; \
        acc[0][nt] = MFMA16(af[0], bf, acc[0][nt]);                                 \
        acc[1][nt] = MFMA16(af[1], bf, acc[1][nt]);                                 \
      }                                                                             \
    }                                                                               \
  }

// ------------------------------------------------- Q = Xb[2048x768] * WqT -> bf16 Q + Qt
__global__ __launch_bounds__(256) void gemm_q_kernel(const short* __restrict__ Xb,
                                                     const short* __restrict__ WqT,
                                                     short* __restrict__ Qo,
                                                     short* __restrict__ Qt) {
  __shared__ short As[64 * 64];
  __shared__ short Bs[64 * 64];
  const int m0 = blockIdx.x * 64;  // token tile
  const int h = blockIdx.y;        // head (N-tile of 64 = HD)
  const int tid = threadIdx.x;
  const int w = tid >> 6, lane = tid & 63, l15 = lane & 15, quad = lane >> 4;
  const short* wqh = WqT + (size_t)h * (HD * EMB);  // [d][e]
  f32x4 acc[4] = {(f32x4){0, 0, 0, 0}, (f32x4){0, 0, 0, 0},
                  (f32x4){0, 0, 0, 0}, (f32x4){0, 0, 0, 0}};
  for (int k0 = 0; k0 < EMB; k0 += 64) {
    stage_direct_bf16(Xb, EMB, m0, k0, As, tid);
    stage_direct_bf16(wqh, EMB, 0, k0, Bs, tid);  // Bs[d][k]
    __syncthreads();
    GEMM_TILE_COMPUTE(As, Bs, acc);
    __syncthreads();
  }
  short* qo = Qo + (size_t)h * (BS_TOK * HD);
#pragma unroll
  for (int nt = 0; nt < 4; ++nt)
#pragma unroll
    for (int r = 0; r < 4; ++r) {
      short v = f2bf(acc[nt][r]);
      int tokr = (w << 4) + (quad << 2) + r;
      int d = (nt << 4) + l15;
      qo[(size_t)(m0 + tokr) * HD + d] = v;
      As[SW64(tokr, d)] = v;
    }
  __syncthreads();
  {  // Qt[h][d][tok], coalesced b128 stores
    int d = tid >> 2, tok0 = (tid & 3) << 4;
    bf16x8 t0, t1;
#pragma unroll
    for (int j = 0; j < 8; ++j) t0[j] = As[SW64(tok0 + j, d)];
#pragma unroll
    for (int j = 0; j < 8; ++j) t1[j] = As[SW64(tok0 + 8 + j, d)];
    short* qt = Qt + (size_t)h * (HD * BS_TOK) + (size_t)d * BS_TOK + m0 + tok0;
    *(bf16x8*)(qt) = t0;
    *(bf16x8*)(qt + 8) = t1;
  }
}

// ------------------------------------------------- flash attention, ksplit=4
__global__ __launch_bounds__(128) void attn_mfma_kernel(const short* __restrict__ Q,
                                                        const short* __restrict__ Qt,
                                                        float* __restrict__ Opart,
                                                        float* __restrict__ Lpart) {
  __shared__ short Ks[64 * 64];      // K[key][d]
  __shared__ short Vt[64 * 64];      // V^T[d][key]
  __shared__ short Pw[2 * 16 * 64];  // per-wave P[qrow][key]
  const int h = blockIdx.y;
  const int q0 = blockIdx.x * 32;
  const int kt0 = blockIdx.z * 8;    // 8 K-tiles per split
  const int tid = threadIdx.x;
  const int lane = tid & 63;
  const int wv = tid >> 6;
  const int l15 = lane & 15;
  const int quad = lane >> 4;
  const short* Qh = Q + (size_t)h * (BS_TOK * HD);
  const short* Qth = Qt + (size_t)h * (HD * BS_TOK);
  short* myP = Pw + wv * 16 * 64;

  bf16x8 qf[2];
  {
    const short* qp = Qh + (size_t)(q0 + wv * 16 + l15) * HD + quad * 8;
    qf[0] = *(const bf16x8*)(qp);
    qf[1] = *(const bf16x8*)(qp + 32);
  }

  f32x4 o[4];
  float lp[4] = {0.f, 0.f, 0.f, 0.f};
#pragma unroll
  for (int r = 0; r < 4; ++r) o[r] = (f32x4){0.f, 0.f, 0.f, 0.f};

  bf16x8 kreg[4], vreg[4];
#pragma unroll
  for (int i = 0; i < 4; ++i) {
    int c = i * 128 + tid;
    kreg[i] = *(const bf16x8*)(Qh + kt0 * 4096 + c * 8);
    vreg[i] = *(const bf16x8*)(Qth + (c >> 3) * BS_TOK + kt0 * 64 + (c & 7) * 8);
  }

  for (int kt = 0; kt < 8; ++kt) {
    __syncthreads();
#pragma unroll
    for (int i = 0; i < 4; ++i) {
      int c = i * 128 + tid, row = c >> 3, g = c & 7;
      *(bf16x8*)&Ks[row * 64 + ((g ^ (row & 7)) << 3)] = kreg[i];
      *(bf16x8*)&Vt[row * 64 + ((g ^ (row & 7)) << 3)] = vreg[i];
    }
    __syncthreads();
    if (kt < 7) {
      int gt = kt0 + kt + 1;
#pragma unroll
      for (int i = 0; i < 4; ++i) {
        int c = i * 128 + tid;
        kreg[i] = *(const bf16x8*)(Qh + gt * 4096 + c * 8);
        vreg[i] = *(const bf16x8*)(Qth + (c >> 3) * BS_TOK + gt * 64 + (c & 7) * 8);
      }
    }

    f32x4 s[4];
#pragma unroll
    for (int ct = 0; ct < 4; ++ct) {
      f32x4 acc = (f32x4){0.f, 0.f, 0.f, 0.f};
#pragma unroll
      for (int ks = 0; ks < 2; ++ks) {
        int row = ct * 16 + l15;
        int c = ks * 4 + quad;
        bf16x8 kf = *(const bf16x8*)(&Ks[row * 64 + ((c ^ (row & 7)) << 3)]);
        acc = MFMA16(qf[ks], kf, acc);
      }
      s[ct] = acc;
    }

#pragma unroll
    for (int ct = 0; ct < 4; ++ct)
#pragma unroll
      for (int r = 0; r < 4; ++r) {
        float p = __expf(s[ct][r] * 0.125f);
        lp[r] += p;
        myP[SW64(quad * 4 + r, ct * 16 + l15)] = f2bf(p);
      }

#pragma unroll
    for (int ks = 0; ks < 2; ++ks) {
      int c = ks * 4 + quad;
      bf16x8 pf = *(const bf16x8*)(&myP[l15 * 64 + ((c ^ (l15 & 7)) << 3)]);
#pragma unroll
      for (int dt = 0; dt < 4; ++dt) {
        int row = dt * 16 + l15;
        bf16x8 vf = *(const bf16x8*)(&Vt[row * 64 + ((c ^ (row & 7)) << 3)]);
        o[dt] = MFMA16(pf, vf, o[dt]);
      }
    }
  }

#pragma unroll
  for (int r = 0; r < 4; ++r) {
    float t = lp[r];
#pragma unroll
    for (int d = 1; d < 16; d <<= 1) t += __shfl_xor(t, d, 64);
    lp[r] = t;
  }
  const int NB = BS_TOK * EMB;
  float* Oh = Opart + (size_t)blockIdx.z * NB + (size_t)h * (BS_TOK * HD);
  float* Lh = Lpart + ((size_t)blockIdx.z * NH + h) * BS_TOK;
#pragma unroll
  for (int r = 0; r < 4; ++r) {
    int qrow = q0 + wv * 16 + quad * 4 + r;
#pragma unroll
    for (int dt = 0; dt < 4; ++dt)
      Oh[(size_t)qrow * HD + dt * 16 + l15] = o[dt][r];
    if (l15 == 0) Lh[qrow] = lp[r];
  }
}

// ------------------------------------------------- combine 4 split partials -> Z bf16
__global__ __launch_bounds__(256) void attn_combine_kernel(const float* __restrict__ Op,
                                                           const float* __restrict__ Lp,
                                                           short* __restrict__ Z) {
  const int NB = BS_TOK * EMB;
  const int NHT = NH * BS_TOK;
  int idx = blockIdx.x * 256 + threadIdx.x;
  float o = Op[idx] + Op[idx + NB] + Op[idx + 2 * NB] + Op[idx + 3 * NB];
  int hq = idx >> 6;
  float l = Lp[hq] + Lp[hq + NHT] + Lp[hq + 2 * NHT] + Lp[hq + 3 * NHT];
  Z[idx] = f2bf(o / l);
}

// ------------------------------------------------- MH = Wo * Zflat, 128x64 tiles, ksplit=2
__global__ __launch_bounds__(256) void gemm_out_kernel(const short* __restrict__ Wob,
                                                       const short* __restrict__ Zc,
                                                       float* __restrict__ Pp) {
  __shared__ short As[128 * 64];
  __shared__ short Bs[64 * 64];
  const int n0 = blockIdx.x * 64;   // j cols (2048 -> 32)
  const int m0 = blockIdx.y * 128;  // e rows (768 -> 6)
  const int kz = blockIdx.z * 384;  // K half
  const int tid = threadIdx.x;
  const int w = tid >> 6, lane = tid & 63, l15 = lane & 15, quad = lane >> 4;
  f32x4 acc[2][4] = {};
  for (int k0 = 0; k0 < 384; k0 += 64) {
    stage_direct128(Wob, EMB, m0, kz + k0, As, tid);
    stage_trans_bf16(Zc, BS_TOK, kz + k0, n0, Bs, tid);  // Bs[n][k] <- Zc[k][n]
    __syncthreads();
    GEMM_TILE_COMPUTE2(As, Bs, acc);
    __syncthreads();
  }
  float* P = Pp + (size_t)blockIdx.z * (BS_TOK * EMB);
#pragma unroll
  for (int u = 0; u < 2; ++u)
#pragma unroll
    for (int nt = 0; nt < 4; ++nt)
#pragma unroll
      for (int r = 0; r < 4; ++r)
        P[(size_t)(m0 + (w << 5) + (u << 4) + (quad << 2) + r) * BS_TOK + n0 +
          (nt << 4) + l15] = acc[u][nt][r];
}

// ------------------------------------------------- FFN = L1b * fwb^T + fb, 128x64, ksplit=2
__global__ __launch_bounds__(256) void gemm_ffn_kernel(const short* __restrict__ L1b,
                                                       const short* __restrict__ Fwb,
                                                       const float* __restrict__ Fb,
                                                       float* __restrict__ Pp) {
  __shared__ short As[128 * 64];
  __shared__ short Bs[64 * 64];
  const int m0 = blockIdx.x * 128;  // token tile (16)
  const int n0 = blockIdx.y * 64;   // out-feature tile (12)
  const int kz = blockIdx.z * 384;  // K half
  const int tid = threadIdx.x;
  const int w = tid >> 6, lane = tid & 63, l15 = lane & 15, quad = lane >> 4;
  f32x4 acc[2][4] = {};
  for (int k0 = 0; k0 < 384; k0 += 64) {
    stage_direct128(L1b, EMB, m0, kz + k0, As, tid);
    stage_direct_bf16(Fwb, EMB, n0, kz + k0, Bs, tid);  // fw[o][k]
    __syncthreads();
    GEMM_TILE_COMPUTE2(As, Bs, acc);
    __syncthreads();
  }
  float* P = Pp + (size_t)blockIdx.z * (BS_TOK * EMB);
  const bool addb = (blockIdx.z == 0);
#pragma unroll
  for (int nt = 0; nt < 4; ++nt) {
    float bias = addb ? Fb[n0 + (nt << 4) + l15] : 0.0f;
#pragma unroll
    for (int u = 0; u < 2; ++u)
#pragma unroll
      for (int r = 0; r < 4; ++r)
        P[(size_t)(m0 + (w << 5) + (u << 4) + (quad << 2) + r) * EMB + n0 +
          (nt << 4) + l15] = acc[u][nt][r] + bias;
  }
}

// ------------------------------------------------- LN(Xa + P0 + P1) -> fp32 + bf16
__global__ __launch_bounds__(256) void ln_kernel(const float* __restrict__ Xa,
                                                 const float* __restrict__ P,
                                                 const float* __restrict__ g,
                                                 const float* __restrict__ bb,
                                                 float* __restrict__ Out,
                                                 short* __restrict__ Outb) {
  __shared__ float red[4];
  const int NB = BS_TOK * EMB;
  const int t = blockIdx.x;
  const int tid = threadIdx.x;
  float v[3];
  float s = 0.f;
#pragma unroll
  for (int i = 0; i < 3; ++i) {
    int e = tid + i * 256;
    int idx = t * EMB + e;
    v[i] = Xa[idx] + P[idx] + P[idx + NB];
    s += v[i];
  }
#pragma unroll
  for (int o = 32; o > 0; o >>= 1) s += __shfl_xor(s, o, 64);
  if ((tid & 63) == 0) red[tid >> 6] = s;
  __syncthreads();
  float mu = (red[0] + red[1] + red[2] + red[3]) * (1.0f / EMB);
  float q = 0.f;
#pragma unroll
  for (int i = 0; i < 3; ++i) {
    float d = v[i] - mu;
    q += d * d;
  }
#pragma unroll
  for (int o = 32; o > 0; o >>= 1) q += __shfl_xor(q, o, 64);
  __syncthreads();
  if ((tid & 63) == 0) red[tid >> 6] = q;
  __syncthreads();
  float var = (red[0] + red[1] + red[2] + red[3]) * (1.0f / EMB);
  float r = rsqrtf(var + 1e-5f);
#pragma unroll
  for (int i = 0; i < 3; ++i) {
    int e = tid + i * 256;
    float res = (v[i] - mu) * r * g[e] + bb[e];
    Out[t * EMB + e] = res;
    Outb[t * EMB + e] = f2bf(res);
  }
}

extern "C" void kernel_launch(void* const* d_in, const int* in_sizes, int n_in,
                              void* d_out, int out_size, void* d_ws, size_t ws_size,
                              hipStream_t stream) {
  const float* tok = (const float*)d_in[0];
  const float* wq = (const float*)d_in[1];
  const float* wo = (const float*)d_in[2];
  const float* g1 = (const float*)d_in[3];
  const float* b1 = (const float*)d_in[4];
  const float* fw = (const float*)d_in[5];
  const float* fb = (const float*)d_in[6];
  const float* g2 = (const float*)d_in[7];
  const float* b2 = (const float*)d_in[8];
  const int NB = BS_TOK * EMB;  // 1572864 elems
  float* bufA = (float*)d_ws;        // X (residual, fp32)
  float* bufB = bufA + NB;           // partial 0 / attn Opart base
  float* bufC = bufB + NB;           // partial 1
  float* bufD = bufC + NB;           // attn Opart 2 / L1 fp32
  float* bufE = bufD + NB;           // attn Opart 3
  short* XbA = (short*)(bufE + NB);  // bf16 of current X
  short* L1b = XbA + NB;             // bf16 of L1
  short* Qbf = L1b + NB;             // Q bf16 [H][2048][64]
  short* Qtb = Qbf + NB;             // Qt bf16 [H][64][2048]
  short* Zbf = Qtb + NB;             // Z bf16 (flat = Zc[768][2048])
  short* wqTb = Zbf + NB;            // wqT bf16 [L][H][64][768]
  short* wob = wqTb + WQN;           // wo bf16 [L][768][768]
  short* fwb = wob + WQN;            // fw bf16 [L][768][768]
  float* Lpart = (float*)(fwb + WQN);  // [4][H][2048]

  cvt_weights_kernel<<<dim3(WQN / (256 * 8), 2), 256, 0, stream>>>(wo, fw, wob, fwb);
  wq_trans_kernel<<<dim3(12, 12 * NH), 256, 0, stream>>>(wq, wqTb);
  pe_add_kernel<<<NB / 256, 256, 0, stream>>>(tok, bufA, XbA);
  for (int it = 0; it < 13; ++it) {
    int l = (it == 0) ? 0 : it - 1;  // layer 0 applied twice (faithful)
    gemm_q_kernel<<<dim3(32, NH), 256, 0, stream>>>(
        XbA, wqTb + (size_t)l * (NH * HD * EMB), Qbf, Qtb);
    attn_mfma_kernel<<<dim3(64, NH, 4), 128, 0, stream>>>(Qbf, Qtb, bufB, Lpart);
    attn_combine_kernel<<<NB / 256, 256, 0, stream>>>(bufB, Lpart, Zbf);
    gemm_out_kernel<<<dim3(32, 6, 2), 256, 0, stream>>>(
        wob + (size_t)l * (EMB * EMB), Zbf, bufB);
    ln_kernel<<<BS_TOK, 256, 0, stream>>>(bufA, bufB, g1 + l * EMB, b1 + l * EMB,
                                          bufD, L1b);
    gemm_ffn_kernel<<<dim3(16, 12, 2), 256, 0, stream>>>(
        L1b, fwb + (size_t)l * (EMB * EMB), fb + l * EMB, bufB);
    float* ln2_dst = (it == 12) ? (float*)d_out : bufA;
    ln_kernel<<<BS_TOK, 256, 0, stream>>>(bufD, bufB, g2 + l * EMB, b2 + l * EMB,
                                          ln2_dst, XbA);
  }
}

// Round 8
// 1231.359 us; speedup vs baseline: 1.0602x; 1.0602x over previous
//
#include <hip/hip_runtime.h>
#include <hip/hip_bf16.h>

// BERT stack: L=12(+1 dup of layer0), H=12, E=768, D=64, B=4, S=512 -> BS=2048 tokens.
// Faithful bugs preserved:
//  - attention flattens batch: 2048 tokens attend to each other globally, q==k==v
//  - zc = z.reshape(768,2048) is a FLAT VIEW of z[H][N][D]  (no transpose)
//  - mh = (wo@zc).reshape(B,S,E) is a FLAT VIEW of mh_mat[768][2048]
//  - pe: p = 10000 for e<384 else 10001; even e -> sin, odd -> cos; s = t % 512
// Inputs/outputs fp32. All GEMMs + attention bf16 MFMA (fp32 accumulate);
// residual/LN chain fp32. Weights pre-converted to bf16 once per launch.
// Attention: no-max softmax => additive partials; ksplit=2 (r7 showed ksplit=4
// regresses: 4x fp32 partial write traffic + fixed cost over fewer tiles).
// Attn block = 256 thr / Q-tile 64: K/V staging shared by 4 waves.
// gemm_out/ffn: 128x64 tiles (wave=32x64, B-frag reuse), ksplit=2; partial
// sum folded into the LN kernel.

#define BS_TOK 2048
#define EMB 768
#define NH 12
#define HD 64
#define WQN (12 * NH * EMB * HD)  // elems per weight stack (7077888)

typedef __attribute__((ext_vector_type(8))) short bf16x8;
typedef __attribute__((ext_vector_type(4))) float f32x4;

__device__ __forceinline__ short f2bf(float f) {
  union { float f; unsigned u; } v;
  v.f = f;
  unsigned r = (v.u + 0x7FFF + ((v.u >> 16) & 1)) >> 16;  // RNE
  return (short)(unsigned short)r;
}

#define MFMA16(a, b, c) __builtin_amdgcn_mfma_f32_16x16x32_bf16(a, b, c, 0, 0, 0)
// XOR-swizzled LDS address for [r][k] tiles, 64-elem rows (zero-conflict, validated r3-r7)
#define SW64(r, k) ((r) * 64 + ((((k) >> 3) ^ ((r) & 7)) << 3) + ((k) & 7))

// ---------------------------------------------------------------- weight prep
__global__ __launch_bounds__(256) void cvt_weights_kernel(const float* __restrict__ wo,
                                                          const float* __restrict__ fw,
                                                          short* __restrict__ wob,
                                                          short* __restrict__ fwb) {
  const float* src = blockIdx.y ? fw : wo;
  short* dst = blockIdx.y ? fwb : wob;
  int i = (blockIdx.x * 256 + threadIdx.x) * 8;
  float4 a = *(const float4*)(src + i);
  float4 b = *(const float4*)(src + i + 4);
  bf16x8 t;
  t[0] = f2bf(a.x); t[1] = f2bf(a.y); t[2] = f2bf(a.z); t[3] = f2bf(a.w);
  t[4] = f2bf(b.x); t[5] = f2bf(b.y); t[6] = f2bf(b.z); t[7] = f2bf(b.w);
  *(bf16x8*)(dst + i) = t;
}

// wqT[l][h][d][e] <- wq[l][h][e][d], bf16
__global__ __launch_bounds__(256) void wq_trans_kernel(const float* __restrict__ wq,
                                                       short* __restrict__ wqT) {
  __shared__ short T[64 * 64];
  const int et = blockIdx.x;  // e-tile (12)
  const int lh = blockIdx.y;  // l*NH+h (144)
  const int tid = threadIdx.x;
  const float* src = wq + ((size_t)lh * EMB + et * 64) * HD;
  {
    int r = tid >> 2, c16 = (tid & 3) << 4;
    const float* p = src + r * HD + c16;
    float4 x0 = *(const float4*)(p + 0);
    float4 x1 = *(const float4*)(p + 4);
    float4 x2 = *(const float4*)(p + 8);
    float4 x3 = *(const float4*)(p + 12);
    bf16x8 a, b;
    a[0] = f2bf(x0.x); a[1] = f2bf(x0.y); a[2] = f2bf(x0.z); a[3] = f2bf(x0.w);
    a[4] = f2bf(x1.x); a[5] = f2bf(x1.y); a[6] = f2bf(x1.z); a[7] = f2bf(x1.w);
    b[0] = f2bf(x2.x); b[1] = f2bf(x2.y); b[2] = f2bf(x2.z); b[3] = f2bf(x2.w);
    b[4] = f2bf(x3.x); b[5] = f2bf(x3.y); b[6] = f2bf(x3.z); b[7] = f2bf(x3.w);
    int g = c16 >> 3;
    *(bf16x8*)&T[r * 64 + ((g ^ (r & 7)) << 3)] = a;
    *(bf16x8*)&T[r * 64 + (((g + 1) ^ (r & 7)) << 3)] = b;
  }
  __syncthreads();
  {
    int d = tid >> 2, e16 = (tid & 3) << 4;
    bf16x8 t0, t1;
#pragma unroll
    for (int j = 0; j < 8; ++j) t0[j] = T[SW64(e16 + j, d)];
#pragma unroll
    for (int j = 0; j < 8; ++j) t1[j] = T[SW64(e16 + 8 + j, d)];
    short* q = wqT + ((size_t)lh * HD + d) * EMB + et * 64 + e16;
    *(bf16x8*)(q) = t0;
    *(bf16x8*)(q + 8) = t1;
  }
}

// ---------------------------------------------------------------- pe + tokens
__global__ __launch_bounds__(256) void pe_add_kernel(const float* __restrict__ tok,
                                                     float* __restrict__ X,
                                                     short* __restrict__ Xb) {
  int idx = blockIdx.x * 256 + threadIdx.x;   // < 2048*768
  int e = idx % EMB;
  int t = idx / EMB;
  int s = t & 511;                            // t = b*512 + s
  float p = (e < 384) ? 10000.0f : 10001.0f;  // 10000 XOR ((2e)//768)
  float ang = (float)s / p;
  float pe = (e & 1) ? cosf(ang) : sinf(ang);
  float v = tok[idx] + pe;
  X[idx] = v;
  Xb[idx] = f2bf(v);
}

// ---------------- staging helpers ----
// 64 rows x 64 k, 256 threads
__device__ __forceinline__ void stage_direct_bf16(const short* __restrict__ src, int ld,
                                                  int row0, int k0, short* dst, int tid) {
  int r = tid >> 2, kb = (tid & 3) << 4;
  const short* p = src + (size_t)(row0 + r) * ld + k0 + kb;
  bf16x8 x0 = *(const bf16x8*)(p);
  bf16x8 x1 = *(const bf16x8*)(p + 8);
  int g = kb >> 3;
  *(bf16x8*)&dst[r * 64 + ((g ^ (r & 7)) << 3)] = x0;
  *(bf16x8*)&dst[r * 64 + (((g + 1) ^ (r & 7)) << 3)] = x1;
}

// 128 rows x 64 k, 256 threads
__device__ __forceinline__ void stage_direct128(const short* __restrict__ src, int ld,
                                                int row0, int k0, short* dst, int tid) {
  int r = tid >> 1, kb = (tid & 1) << 5;
  const short* p = src + (size_t)(row0 + r) * ld + k0 + kb;
  bf16x8 x0 = *(const bf16x8*)(p);
  bf16x8 x1 = *(const bf16x8*)(p + 8);
  bf16x8 x2 = *(const bf16x8*)(p + 16);
  bf16x8 x3 = *(const bf16x8*)(p + 24);
  int g = kb >> 3;
  *(bf16x8*)&dst[r * 64 + (((g + 0) ^ (r & 7)) << 3)] = x0;
  *(bf16x8*)&dst[r * 64 + (((g + 1) ^ (r & 7)) << 3)] = x1;
  *(bf16x8*)&dst[r * 64 + (((g + 2) ^ (r & 7)) << 3)] = x2;
  *(bf16x8*)&dst[r * 64 + (((g + 3) ^ (r & 7)) << 3)] = x3;
}

// transpose: dst[n][k] <- bf16 src[k0+k][col0+n] (n contig in src)
__device__ __forceinline__ void stage_trans_bf16(const short* __restrict__ src, int ld,
                                                 int k0, int col0, short* dst, int tid) {
  int kk = tid >> 2, nb = (tid & 3) << 4;
  const short* p = src + (size_t)(k0 + kk) * ld + col0 + nb;
  bf16x8 x0 = *(const bf16x8*)(p + 0);
  bf16x8 x1 = *(const bf16x8*)(p + 8);
#pragma unroll
  for (int j = 0; j < 8; ++j) dst[SW64(nb + j, kk)] = x0[j];
#pragma unroll
  for (int j = 0; j < 8; ++j) dst[SW64(nb + 8 + j, kk)] = x1[j];
}

// wave computes 16 rows x 64 cols (64x64 block tile, 4 waves)
#define GEMM_TILE_COMPUTE(As, Bs, acc)                                              \
  {                                                                                 \
    _Pragma("unroll") for (int s = 0; s < 2; ++s) {                                 \
      int ra = (w << 4) + l15;                                                      \
      bf16x8 af = *(const bf16x8*)&As[ra * 64 + ((((s << 2) + quad) ^ (ra & 7)) << 3)]; \
      _Pragma("unroll") for (int nt = 0; nt < 4; ++nt) {                            \
        int rb = (nt << 4) + l15;                                                   \
        bf16x8 bf = *(const bf16x8*)&Bs[rb * 64 + ((((s << 2) + quad) ^ (rb & 7)) << 3)]; \
        acc[nt] = MFMA16(af, bf, acc[nt]);                                          \
      }                                                                             \
    }                                                                               \
  }

// wave computes 32 rows x 64 cols (128x64 block tile, 4 waves); B-frag reused 2x
#define GEMM_TILE_COMPUTE2(As, Bs, acc)                                             \
  {                                                                                 \
    _Pragma("unroll") for (int s = 0; s < 2; ++s) {                                 \
      bf16x8 af[2];                                                                 \
      _Pragma("unroll") for (int u = 0; u < 2; ++u) {                               \
        int ra = (w << 5) + (u << 4) + l15;                                         \
        af[u] = *(const bf16x8*)&As[ra * 64 + ((((s << 2) + quad) ^ (ra & 7)) << 3)]; \
      }                                                                             \
      _Pragma("unroll") for (int nt = 0; nt < 4; ++nt) {                            \
        int rb = (nt << 4) + l15;                                                   \
        bf16x8 bf = *(const bf16x8*)&Bs[rb * 64 + ((((s << 2) + quad) ^ (rb & 7)) << 3)]; \
        acc[0][nt] = MFMA16(af[0], bf, acc[0][nt]);                                 \
        acc[1][nt] = MFMA16(af[1], bf, acc[1][nt]);                                 \
      }                                                                             \
    }                                                                               \
  }

// ------------------------------------------------- Q = Xb[2048x768] * WqT -> bf16 Q + Qt
__global__ __launch_bounds__(256) void gemm_q_kernel(const short* __restrict__ Xb,
                                                     const short* __restrict__ WqT,
                                                     short* __restrict__ Qo,
                                                     short* __restrict__ Qt) {
  __shared__ short As[64 * 64];
  __shared__ short Bs[64 * 64];
  const int m0 = blockIdx.x * 64;  // token tile
  const int h = blockIdx.y;        // head (N-tile of 64 = HD)
  const int tid = threadIdx.x;
  const int w = tid >> 6, lane = tid & 63, l15 = lane & 15, quad = lane >> 4;
  const short* wqh = WqT + (size_t)h * (HD * EMB);  // [d][e]
  f32x4 acc[4] = {(f32x4){0, 0, 0, 0}, (f32x4){0, 0, 0, 0},
                  (f32x4){0, 0, 0, 0}, (f32x4){0, 0, 0, 0}};
  for (int k0 = 0; k0 < EMB; k0 += 64) {
    stage_direct_bf16(Xb, EMB, m0, k0, As, tid);
    stage_direct_bf16(wqh, EMB, 0, k0, Bs, tid);  // Bs[d][k]
    __syncthreads();
    GEMM_TILE_COMPUTE(As, Bs, acc);
    __syncthreads();
  }
  short* qo = Qo + (size_t)h * (BS_TOK * HD);
#pragma unroll
  for (int nt = 0; nt < 4; ++nt)
#pragma unroll
    for (int r = 0; r < 4; ++r) {
      short v = f2bf(acc[nt][r]);
      int tokr = (w << 4) + (quad << 2) + r;
      int d = (nt << 4) + l15;
      qo[(size_t)(m0 + tokr) * HD + d] = v;
      As[SW64(tokr, d)] = v;
    }
  __syncthreads();
  {  // Qt[h][d][tok], coalesced b128 stores
    int d = tid >> 2, tok0 = (tid & 3) << 4;
    bf16x8 t0, t1;
#pragma unroll
    for (int j = 0; j < 8; ++j) t0[j] = As[SW64(tok0 + j, d)];
#pragma unroll
    for (int j = 0; j < 8; ++j) t1[j] = As[SW64(tok0 + 8 + j, d)];
    short* qt = Qt + (size_t)h * (HD * BS_TOK) + (size_t)d * BS_TOK + m0 + tok0;
    *(bf16x8*)(qt) = t0;
    *(bf16x8*)(qt + 8) = t1;
  }
}

// ------------------------------------------------- flash attention
// 256 thr (4 waves), Q-tile 64 (16 rows/wave), K-tile 64, ksplit=2.
// K/V staging shared by 4 waves; no-max softmax, additive partials.
__global__ __launch_bounds__(256) void attn_mfma_kernel(const short* __restrict__ Q,
                                                        const short* __restrict__ Qt,
                                                        float* __restrict__ Opart,
                                                        float* __restrict__ Lpart) {
  __shared__ short Ks[64 * 64];      // K[key][d]
  __shared__ short Vt[64 * 64];      // V^T[d][key]
  __shared__ short Pw[4 * 16 * 64];  // per-wave P[qrow][key]
  const int h = blockIdx.y;
  const int q0 = blockIdx.x * 64;
  const int kt0 = blockIdx.z * 16;   // 16 K-tiles per split
  const int tid = threadIdx.x;
  const int lane = tid & 63;
  const int wv = tid >> 6;
  const int l15 = lane & 15;
  const int quad = lane >> 4;
  const short* Qh = Q + (size_t)h * (BS_TOK * HD);
  const short* Qth = Qt + (size_t)h * (HD * BS_TOK);
  short* myP = Pw + wv * 16 * 64;

  bf16x8 qf[2];
  {
    const short* qp = Qh + (size_t)(q0 + wv * 16 + l15) * HD + quad * 8;
    qf[0] = *(const bf16x8*)(qp);
    qf[1] = *(const bf16x8*)(qp + 32);
  }

  f32x4 o[4];
  float lp[4] = {0.f, 0.f, 0.f, 0.f};
#pragma unroll
  for (int r = 0; r < 4; ++r) o[r] = (f32x4){0.f, 0.f, 0.f, 0.f};

  // 2+2 b128 chunks per thread per tile (512 chunks per 8KB tile, 256 thr)
  bf16x8 kreg[2], vreg[2];
#pragma unroll
  for (int i = 0; i < 2; ++i) {
    int c = i * 256 + tid;
    kreg[i] = *(const bf16x8*)(Qh + kt0 * 4096 + c * 8);
    vreg[i] = *(const bf16x8*)(Qth + (c >> 3) * BS_TOK + kt0 * 64 + (c & 7) * 8);
  }

  for (int kt = 0; kt < 16; ++kt) {
    __syncthreads();
#pragma unroll
    for (int i = 0; i < 2; ++i) {
      int c = i * 256 + tid, row = c >> 3, g = c & 7;
      *(bf16x8*)&Ks[row * 64 + ((g ^ (row & 7)) << 3)] = kreg[i];
      *(bf16x8*)&Vt[row * 64 + ((g ^ (row & 7)) << 3)] = vreg[i];
    }
    __syncthreads();
    if (kt < 15) {
      int gt = kt0 + kt + 1;
#pragma unroll
      for (int i = 0; i < 2; ++i) {
        int c = i * 256 + tid;
        kreg[i] = *(const bf16x8*)(Qh + gt * 4096 + c * 8);
        vreg[i] = *(const bf16x8*)(Qth + (c >> 3) * BS_TOK + gt * 64 + (c & 7) * 8);
      }
    }

    // S = Q K^T  (4 col-tiles of 16 keys)
    f32x4 s[4];
#pragma unroll
    for (int ct = 0; ct < 4; ++ct) {
      f32x4 acc = (f32x4){0.f, 0.f, 0.f, 0.f};
#pragma unroll
      for (int ks = 0; ks < 2; ++ks) {
        int row = ct * 16 + l15;
        int c = ks * 4 + quad;
        bf16x8 kf = *(const bf16x8*)(&Ks[row * 64 + ((c ^ (row & 7)) << 3)]);
        acc = MFMA16(qf[ks], kf, acc);
      }
      s[ct] = acc;
    }

    // no-max softmax: p = exp(s/8); per-lane partial denominator only
#pragma unroll
    for (int ct = 0; ct < 4; ++ct)
#pragma unroll
      for (int r = 0; r < 4; ++r) {
        float p = __expf(s[ct][r] * 0.125f);
        lp[r] += p;
        myP[SW64(quad * 4 + r, ct * 16 + l15)] = f2bf(p);
      }

    // O += P V  (wave-local myP; in-wave lgkmcnt ordering, no barrier)
#pragma unroll
    for (int ks = 0; ks < 2; ++ks) {
      int c = ks * 4 + quad;
      bf16x8 pf = *(const bf16x8*)(&myP[l15 * 64 + ((c ^ (l15 & 7)) << 3)]);
#pragma unroll
      for (int dt = 0; dt < 4; ++dt) {
        int row = dt * 16 + l15;
        bf16x8 vf = *(const bf16x8*)(&Vt[row * 64 + ((c ^ (row & 7)) << 3)]);
        o[dt] = MFMA16(pf, vf, o[dt]);
      }
    }
  }

#pragma unroll
  for (int r = 0; r < 4; ++r) {
    float t = lp[r];
#pragma unroll
    for (int d = 1; d < 16; d <<= 1) t += __shfl_xor(t, d, 64);
    lp[r] = t;
  }
  const int NB = BS_TOK * EMB;
  float* Oh = Opart + (size_t)blockIdx.z * NB + (size_t)h * (BS_TOK * HD);
  float* Lh = Lpart + ((size_t)blockIdx.z * NH + h) * BS_TOK;
#pragma unroll
  for (int r = 0; r < 4; ++r) {
    int qrow = q0 + wv * 16 + quad * 4 + r;
#pragma unroll
    for (int dt = 0; dt < 4; ++dt)
      Oh[(size_t)qrow * HD + dt * 16 + l15] = o[dt][r];
    if (l15 == 0) Lh[qrow] = lp[r];
  }
}

// ------------------------------------------------- combine 2 split partials -> Z bf16
__global__ __launch_bounds__(256) void attn_combine_kernel(const float* __restrict__ Op,
                                                           const float* __restrict__ Lp,
                                                           short* __restrict__ Z) {
  const int NB = BS_TOK * EMB;
  const int NHT = NH * BS_TOK;
  int idx = blockIdx.x * 256 + threadIdx.x;
  float o = Op[idx] + Op[idx + NB];
  int hq = idx >> 6;
  float l = Lp[hq] + Lp[hq + NHT];
  Z[idx] = f2bf(o / l);
}

// ------------------------------------------------- MH = Wo * Zflat, 128x64 tiles, ksplit=2
__global__ __launch_bounds__(256) void gemm_out_kernel(const short* __restrict__ Wob,
                                                       const short* __restrict__ Zc,
                                                       float* __restrict__ Pp) {
  __shared__ short As[128 * 64];
  __shared__ short Bs[64 * 64];
  const int n0 = blockIdx.x * 64;   // j cols (2048 -> 32)
  const int m0 = blockIdx.y * 128;  // e rows (768 -> 6)
  const int kz = blockIdx.z * 384;  // K half
  const int tid = threadIdx.x;
  const int w = tid >> 6, lane = tid & 63, l15 = lane & 15, quad = lane >> 4;
  f32x4 acc[2][4] = {};
  for (int k0 = 0; k0 < 384; k0 += 64) {
    stage_direct128(Wob, EMB, m0, kz + k0, As, tid);
    stage_trans_bf16(Zc, BS_TOK, kz + k0, n0, Bs, tid);  // Bs[n][k] <- Zc[k][n]
    __syncthreads();
    GEMM_TILE_COMPUTE2(As, Bs, acc);
    __syncthreads();
  }
  float* P = Pp + (size_t)blockIdx.z * (BS_TOK * EMB);
#pragma unroll
  for (int u = 0; u < 2; ++u)
#pragma unroll
    for (int nt = 0; nt < 4; ++nt)
#pragma unroll
      for (int r = 0; r < 4; ++r)
        P[(size_t)(m0 + (w << 5) + (u << 4) + (quad << 2) + r) * BS_TOK + n0 +
          (nt << 4) + l15] = acc[u][nt][r];
}

// ------------------------------------------------- FFN = L1b * fwb^T + fb, 128x64, ksplit=2
__global__ __launch_bounds__(256) void gemm_ffn_kernel(const short* __restrict__ L1b,
                                                       const short* __restrict__ Fwb,
                                                       const float* __restrict__ Fb,
                                                       float* __restrict__ Pp) {
  __shared__ short As[128 * 64];
  __shared__ short Bs[64 * 64];
  const int m0 = blockIdx.x * 128;  // token tile (16)
  const int n0 = blockIdx.y * 64;   // out-feature tile (12)
  const int kz = blockIdx.z * 384;  // K half
  const int tid = threadIdx.x;
  const int w = tid >> 6, lane = tid & 63, l15 = lane & 15, quad = lane >> 4;
  f32x4 acc[2][4] = {};
  for (int k0 = 0; k0 < 384; k0 += 64) {
    stage_direct128(L1b, EMB, m0, kz + k0, As, tid);
    stage_direct_bf16(Fwb, EMB, n0, kz + k0, Bs, tid);  // fw[o][k]
    __syncthreads();
    GEMM_TILE_COMPUTE2(As, Bs, acc);
    __syncthreads();
  }
  float* P = Pp + (size_t)blockIdx.z * (BS_TOK * EMB);
  const bool addb = (blockIdx.z == 0);
#pragma unroll
  for (int nt = 0; nt < 4; ++nt) {
    float bias = addb ? Fb[n0 + (nt << 4) + l15] : 0.0f;
#pragma unroll
    for (int u = 0; u < 2; ++u)
#pragma unroll
      for (int r = 0; r < 4; ++r)
        P[(size_t)(m0 + (w << 5) + (u << 4) + (quad << 2) + r) * EMB + n0 +
          (nt << 4) + l15] = acc[u][nt][r] + bias;
  }
}

// ------------------------------------------------- LN(Xa + P0 + P1) -> fp32 + bf16
__global__ __launch_bounds__(256) void ln_kernel(const float* __restrict__ Xa,
                                                 const float* __restrict__ P,
                                                 const float* __restrict__ g,
                                                 const float* __restrict__ bb,
                                                 float* __restrict__ Out,
                                                 short* __restrict__ Outb) {
  __shared__ float red[4];
  const int NB = BS_TOK * EMB;
  const int t = blockIdx.x;
  const int tid = threadIdx.x;
  float v[3];
  float s = 0.f;
#pragma unroll
  for (int i = 0; i < 3; ++i) {
    int e = tid + i * 256;
    int idx = t * EMB + e;
    v[i] = Xa[idx] + P[idx] + P[idx + NB];
    s += v[i];
  }
#pragma unroll
  for (int o = 32; o > 0; o >>= 1) s += __shfl_xor(s, o, 64);
  if ((tid & 63) == 0) red[tid >> 6] = s;
  __syncthreads();
  float mu = (red[0] + red[1] + red[2] + red[3]) * (1.0f / EMB);
  float q = 0.f;
#pragma unroll
  for (int i = 0; i < 3; ++i) {
    float d = v[i] - mu;
    q += d * d;
  }
#pragma unroll
  for (int o = 32; o > 0; o >>= 1) q += __shfl_xor(q, o, 64);
  __syncthreads();
  if ((tid & 63) == 0) red[tid >> 6] = q;
  __syncthreads();
  float var = (red[0] + red[1] + red[2] + red[3]) * (1.0f / EMB);
  float r = rsqrtf(var + 1e-5f);
#pragma unroll
  for (int i = 0; i < 3; ++i) {
    int e = tid + i * 256;
    float res = (v[i] - mu) * r * g[e] + bb[e];
    Out[t * EMB + e] = res;
    Outb[t * EMB + e] = f2bf(res);
  }
}

extern "C" void kernel_launch(void* const* d_in, const int* in_sizes, int n_in,
                              void* d_out, int out_size, void* d_ws, size_t ws_size,
                              hipStream_t stream) {
  const float* tok = (const float*)d_in[0];
  const float* wq = (const float*)d_in[1];
  const float* wo = (const float*)d_in[2];
  const float* g1 = (const float*)d_in[3];
  const float* b1 = (const float*)d_in[4];
  const float* fw = (const float*)d_in[5];
  const float* fb = (const float*)d_in[6];
  const float* g2 = (const float*)d_in[7];
  const float* b2 = (const float*)d_in[8];
  const int NB = BS_TOK * EMB;  // 1572864 elems
  float* bufA = (float*)d_ws;        // X (residual, fp32)
  float* bufB = bufA + NB;           // partial 0 (attn O / gemm)
  float* bufC = bufB + NB;           // partial 1
  float* bufD = bufC + NB;           // L1 fp32
  short* XbA = (short*)(bufD + NB);  // bf16 of current X
  short* L1b = XbA + NB;             // bf16 of L1
  short* Qbf = L1b + NB;             // Q bf16 [H][2048][64]
  short* Qtb = Qbf + NB;             // Qt bf16 [H][64][2048]
  short* Zbf = Qtb + NB;             // Z bf16 (flat = Zc[768][2048])
  short* wqTb = Zbf + NB;            // wqT bf16 [L][H][64][768]
  short* wob = wqTb + WQN;           // wo bf16 [L][768][768]
  short* fwb = wob + WQN;            // fw bf16 [L][768][768]
  float* Lpart = (float*)(fwb + WQN);  // [2][H][2048]

  cvt_weights_kernel<<<dim3(WQN / (256 * 8), 2), 256, 0, stream>>>(wo, fw, wob, fwb);
  wq_trans_kernel<<<dim3(12, 12 * NH), 256, 0, stream>>>(wq, wqTb);
  pe_add_kernel<<<NB / 256, 256, 0, stream>>>(tok, bufA, XbA);
  for (int it = 0; it < 13; ++it) {
    int l = (it == 0) ? 0 : it - 1;  // layer 0 applied twice (faithful)
    gemm_q_kernel<<<dim3(32, NH), 256, 0, stream>>>(
        XbA, wqTb + (size_t)l * (NH * HD * EMB), Qbf, Qtb);
    attn_mfma_kernel<<<dim3(32, NH, 2), 256, 0, stream>>>(Qbf, Qtb, bufB, Lpart);
    attn_combine_kernel<<<NB / 256, 256, 0, stream>>>(bufB, Lpart, Zbf);
    gemm_out_kernel<<<dim3(32, 6, 2), 256, 0, stream>>>(
        wob + (size_t)l * (EMB * EMB), Zbf, bufB);
    ln_kernel<<<BS_TOK, 256, 0, stream>>>(bufA, bufB, g1 + l * EMB, b1 + l * EMB,
                                          bufD, L1b);
    gemm_ffn_kernel<<<dim3(16, 12, 2), 256, 0, stream>>>(
        L1b, fwb + (size_t)l * (EMB * EMB), fb + l * EMB, bufB);
    float* ln2_dst = (it == 12) ? (float*)d_out : bufA;
    ln_kernel<<<BS_TOK, 256, 0, stream>>>(bufD, bufB, g2 + l * EMB, b2 + l * EMB,
                                          ln2_dst, XbA);
  }
}

// Round 9
// 1170.514 us; speedup vs baseline: 1.1153x; 1.0520x over previous
//
#include <hip/hip_runtime.h>
#include <hip/hip_bf16.h>

// BERT stack: L=12(+1 dup of layer0), H=12, E=768, D=64, B=4, S=512 -> BS=2048 tokens.
// Faithful bugs preserved:
//  - attention flattens batch: 2048 tokens attend to each other globally, q==k==v
//  - zc = z.reshape(768,2048) is a FLAT VIEW of z[H][N][D]  (no transpose)
//  - mh = (wo@zc).reshape(B,S,E) is a FLAT VIEW of mh_mat[768][2048]
//  - pe: p = 10000 for e<384 else 10001; even e -> sin, odd -> cos; s = t % 512
// Inputs/outputs fp32. All GEMMs + attention bf16 MFMA (fp32 accumulate);
// residual/LN chain fp32. Weights pre-converted to bf16 once per launch.
// Attention: no-max softmax => additive partials, ksplit=2; S^T operand swap
// (qrow=lane&15) makes P->LDS 4xb64 and denominator a per-lane scalar.
// attn_combine is FUSED into gemm_out's B-staging (partial-sum + 1/l + f2bf);
// attn fp32 partials are L3-resident when gemm_out re-reads them.

#define BS_TOK 2048
#define EMB 768
#define NH 12
#define HD 64
#define WQN (12 * NH * EMB * HD)  // elems per weight stack (7077888)

typedef __attribute__((ext_vector_type(8))) short bf16x8;
typedef __attribute__((ext_vector_type(4))) short bf16x4;
typedef __attribute__((ext_vector_type(4))) float f32x4;

__device__ __forceinline__ short f2bf(float f) {
  union { float f; unsigned u; } v;
  v.f = f;
  unsigned r = (v.u + 0x7FFF + ((v.u >> 16) & 1)) >> 16;  // RNE
  return (short)(unsigned short)r;
}

#define MFMA16(a, b, c) __builtin_amdgcn_mfma_f32_16x16x32_bf16(a, b, c, 0, 0, 0)
// XOR-swizzled LDS address for [r][k] tiles, 64-elem rows (zero-conflict, validated r3-r8)
#define SW64(r, k) ((r) * 64 + ((((k) >> 3) ^ ((r) & 7)) << 3) + ((k) & 7))

// ---------------------------------------------------------------- weight prep
__global__ __launch_bounds__(256) void cvt_weights_kernel(const float* __restrict__ wo,
                                                          const float* __restrict__ fw,
                                                          short* __restrict__ wob,
                                                          short* __restrict__ fwb) {
  const float* src = blockIdx.y ? fw : wo;
  short* dst = blockIdx.y ? fwb : wob;
  int i = (blockIdx.x * 256 + threadIdx.x) * 8;
  float4 a = *(const float4*)(src + i);
  float4 b = *(const float4*)(src + i + 4);
  bf16x8 t;
  t[0] = f2bf(a.x); t[1] = f2bf(a.y); t[2] = f2bf(a.z); t[3] = f2bf(a.w);
  t[4] = f2bf(b.x); t[5] = f2bf(b.y); t[6] = f2bf(b.z); t[7] = f2bf(b.w);
  *(bf16x8*)(dst + i) = t;
}

// wqT[l][h][d][e] <- wq[l][h][e][d], bf16
__global__ __launch_bounds__(256) void wq_trans_kernel(const float* __restrict__ wq,
                                                       short* __restrict__ wqT) {
  __shared__ short T[64 * 64];
  const int et = blockIdx.x;  // e-tile (12)
  const int lh = blockIdx.y;  // l*NH+h (144)
  const int tid = threadIdx.x;
  const float* src = wq + ((size_t)lh * EMB + et * 64) * HD;
  {
    int r = tid >> 2, c16 = (tid & 3) << 4;
    const float* p = src + r * HD + c16;
    float4 x0 = *(const float4*)(p + 0);
    float4 x1 = *(const float4*)(p + 4);
    float4 x2 = *(const float4*)(p + 8);
    float4 x3 = *(const float4*)(p + 12);
    bf16x8 a, b;
    a[0] = f2bf(x0.x); a[1] = f2bf(x0.y); a[2] = f2bf(x0.z); a[3] = f2bf(x0.w);
    a[4] = f2bf(x1.x); a[5] = f2bf(x1.y); a[6] = f2bf(x1.z); a[7] = f2bf(x1.w);
    b[0] = f2bf(x2.x); b[1] = f2bf(x2.y); b[2] = f2bf(x2.z); b[3] = f2bf(x2.w);
    b[4] = f2bf(x3.x); b[5] = f2bf(x3.y); b[6] = f2bf(x3.z); b[7] = f2bf(x3.w);
    int g = c16 >> 3;
    *(bf16x8*)&T[r * 64 + ((g ^ (r & 7)) << 3)] = a;
    *(bf16x8*)&T[r * 64 + (((g + 1) ^ (r & 7)) << 3)] = b;
  }
  __syncthreads();
  {
    int d = tid >> 2, e16 = (tid & 3) << 4;
    bf16x8 t0, t1;
#pragma unroll
    for (int j = 0; j < 8; ++j) t0[j] = T[SW64(e16 + j, d)];
#pragma unroll
    for (int j = 0; j < 8; ++j) t1[j] = T[SW64(e16 + 8 + j, d)];
    short* q = wqT + ((size_t)lh * HD + d) * EMB + et * 64 + e16;
    *(bf16x8*)(q) = t0;
    *(bf16x8*)(q + 8) = t1;
  }
}

// ---------------------------------------------------------------- pe + tokens
__global__ __launch_bounds__(256) void pe_add_kernel(const float* __restrict__ tok,
                                                     float* __restrict__ X,
                                                     short* __restrict__ Xb) {
  int idx = blockIdx.x * 256 + threadIdx.x;   // < 2048*768
  int e = idx % EMB;
  int t = idx / EMB;
  int s = t & 511;                            // t = b*512 + s
  float p = (e < 384) ? 10000.0f : 10001.0f;  // 10000 XOR ((2e)//768)
  float ang = (float)s / p;
  float pe = (e & 1) ? cosf(ang) : sinf(ang);
  float v = tok[idx] + pe;
  X[idx] = v;
  Xb[idx] = f2bf(v);
}

// ---------------- staging helpers ----
// 64 rows x 64 k, 256 threads
__device__ __forceinline__ void stage_direct_bf16(const short* __restrict__ src, int ld,
                                                  int row0, int k0, short* dst, int tid) {
  int r = tid >> 2, kb = (tid & 3) << 4;
  const short* p = src + (size_t)(row0 + r) * ld + k0 + kb;
  bf16x8 x0 = *(const bf16x8*)(p);
  bf16x8 x1 = *(const bf16x8*)(p + 8);
  int g = kb >> 3;
  *(bf16x8*)&dst[r * 64 + ((g ^ (r & 7)) << 3)] = x0;
  *(bf16x8*)&dst[r * 64 + (((g + 1) ^ (r & 7)) << 3)] = x1;
}

// 128 rows x 64 k, 256 threads
__device__ __forceinline__ void stage_direct128(const short* __restrict__ src, int ld,
                                                int row0, int k0, short* dst, int tid) {
  int r = tid >> 1, kb = (tid & 1) << 5;
  const short* p = src + (size_t)(row0 + r) * ld + k0 + kb;
  bf16x8 x0 = *(const bf16x8*)(p);
  bf16x8 x1 = *(const bf16x8*)(p + 8);
  bf16x8 x2 = *(const bf16x8*)(p + 16);
  bf16x8 x3 = *(const bf16x8*)(p + 24);
  int g = kb >> 3;
  *(bf16x8*)&dst[r * 64 + (((g + 0) ^ (r & 7)) << 3)] = x0;
  *(bf16x8*)&dst[r * 64 + (((g + 1) ^ (r & 7)) << 3)] = x1;
  *(bf16x8*)&dst[r * 64 + (((g + 2) ^ (r & 7)) << 3)] = x2;
  *(bf16x8*)&dst[r * 64 + (((g + 3) ^ (r & 7)) << 3)] = x3;
}

// fused combine+transpose staging for gemm_out:
// dst[n][k] <- bf16( (Op0+Op1)[(k0+k)*2048 + col0+n] / (Lp0+Lp1)[token] )
__device__ __forceinline__ void stage_trans_comb(const float* __restrict__ Op,
                                                 const float* __restrict__ Lp,
                                                 int k0, int col0, short* dst, int tid) {
  const int NB = BS_TOK * EMB;
  const int NHT = NH * BS_TOK;
  int kk = tid >> 2, nb = (tid & 3) << 4;
  size_t base = (size_t)(k0 + kk) * BS_TOK + col0 + nb;
  int hq = (int)(base >> 6);  // constant across the 16 cols (col0%64==0, nb+j<64)
  float rl = 1.0f / (Lp[hq] + Lp[hq + NHT]);
#pragma unroll
  for (int q4 = 0; q4 < 4; ++q4) {
    float4 a = *(const float4*)(Op + base + q4 * 4);
    float4 b = *(const float4*)(Op + base + NB + q4 * 4);
    dst[SW64(nb + q4 * 4 + 0, kk)] = f2bf((a.x + b.x) * rl);
    dst[SW64(nb + q4 * 4 + 1, kk)] = f2bf((a.y + b.y) * rl);
    dst[SW64(nb + q4 * 4 + 2, kk)] = f2bf((a.z + b.z) * rl);
    dst[SW64(nb + q4 * 4 + 3, kk)] = f2bf((a.w + b.w) * rl);
  }
}

// wave computes 16 rows x 64 cols (64x64 block tile, 4 waves)
#define GEMM_TILE_COMPUTE(As, Bs, acc)                                              \
  {                                                                                 \
    _Pragma("unroll") for (int s = 0; s < 2; ++s) {                                 \
      int ra = (w << 4) + l15;                                                      \
      bf16x8 af = *(const bf16x8*)&As[ra * 64 + ((((s << 2) + quad) ^ (ra & 7)) << 3)]; \
      _Pragma("unroll") for (int nt = 0; nt < 4; ++nt) {                            \
        int rb = (nt << 4) + l15;                                                   \
        bf16x8 bf = *(const bf16x8*)&Bs[rb * 64 + ((((s << 2) + quad) ^ (rb & 7)) << 3)]; \
        acc[nt] = MFMA16(af, bf, acc[nt]);                                          \
      }                                                                             \
    }                                                                               \
  }

// wave computes 32 rows x 64 cols (128x64 block tile, 4 waves); B-frag reused 2x
#define GEMM_TILE_COMPUTE2(As, Bs, acc)                                             \
  {                                                                                 \
    _Pragma("unroll") for (int s = 0; s < 2; ++s) {                                 \
      bf16x8 af[2];                                                                 \
      _Pragma("unroll") for (int u = 0; u < 2; ++u) {                               \
        int ra = (w << 5) + (u << 4) + l15;                                         \
        af[u] = *(const bf16x8*)&As[ra * 64 + ((((s << 2) + quad) ^ (ra & 7)) << 3)]; \
      }                                                                             \
      _Pragma("unroll") for (int nt = 0; nt < 4; ++nt) {                            \
        int rb = (nt << 4) + l15;                                                   \
        bf16x8 bf = *(const bf16x8*)&Bs[rb * 64 + ((((s << 2) + quad) ^ (rb & 7)) << 3)]; \
        acc[0][nt] = MFMA16(af[0], bf, acc[0][nt]);                                 \
        acc[1][nt] = MFMA16(af[1], bf, acc[1][nt]);                                 \
      }                                                                             \
    }                                                                               \
  }

// ------------------------------------------------- Q = Xb[2048x768] * WqT -> bf16 Q + Qt
__global__ __launch_bounds__(256) void gemm_q_kernel(const short* __restrict__ Xb,
                                                     const short* __restrict__ WqT,
                                                     short* __restrict__ Qo,
                                                     short* __restrict__ Qt) {
  __shared__ short As[64 * 64];
  __shared__ short Bs[64 * 64];
  const int m0 = blockIdx.x * 64;  // token tile
  const int h = blockIdx.y;        // head (N-tile of 64 = HD)
  const int tid = threadIdx.x;
  const int w = tid >> 6, lane = tid & 63, l15 = lane & 15, quad = lane >> 4;
  const short* wqh = WqT + (size_t)h * (HD * EMB);  // [d][e]
  f32x4 acc[4] = {(f32x4){0, 0, 0, 0}, (f32x4){0, 0, 0, 0},
                  (f32x4){0, 0, 0, 0}, (f32x4){0, 0, 0, 0}};
  for (int k0 = 0; k0 < EMB; k0 += 64) {
    stage_direct_bf16(Xb, EMB, m0, k0, As, tid);
    stage_direct_bf16(wqh, EMB, 0, k0, Bs, tid);  // Bs[d][k]
    __syncthreads();
    GEMM_TILE_COMPUTE(As, Bs, acc);
    __syncthreads();
  }
  // stage result tile into As as [tok][d]
#pragma unroll
  for (int nt = 0; nt < 4; ++nt)
#pragma unroll
    for (int r = 0; r < 4; ++r)
      As[SW64((w << 4) + (quad << 2) + r, (nt << 4) + l15)] = f2bf(acc[nt][r]);
  __syncthreads();
  {  // Qo[h][tok][d], coalesced b128 stores
    int r2 = tid >> 2, kb = (tid & 3) << 4;
    int g = kb >> 3;
    bf16x8 q0v = *(const bf16x8*)&As[r2 * 64 + ((g ^ (r2 & 7)) << 3)];
    bf16x8 q1v = *(const bf16x8*)&As[r2 * 64 + (((g + 1) ^ (r2 & 7)) << 3)];
    short* qo = Qo + (size_t)h * (BS_TOK * HD) + (size_t)(m0 + r2) * HD + kb;
    *(bf16x8*)(qo) = q0v;
    *(bf16x8*)(qo + 8) = q1v;
  }
  {  // Qt[h][d][tok], coalesced b128 stores
    int d = tid >> 2, tok0 = (tid & 3) << 4;
    bf16x8 t0, t1;
#pragma unroll
    for (int j = 0; j < 8; ++j) t0[j] = As[SW64(tok0 + j, d)];
#pragma unroll
    for (int j = 0; j < 8; ++j) t1[j] = As[SW64(tok0 + 8 + j, d)];
    short* qt = Qt + (size_t)h * (HD * BS_TOK) + (size_t)d * BS_TOK + m0 + tok0;
    *(bf16x8*)(qt) = t0;
    *(bf16x8*)(qt + 8) = t1;
  }
}

// ------------------------------------------------- flash attention
// 256 thr (4 waves), Q-tile 64 (16 rows/wave), K-tile 64, ksplit=2.
// S^T operand swap: MFMA(kf, qf) -> lane holds qrow=l15, keys=ct*16+quad*4+r.
// P->LDS: 4 x b64; denominator: per-lane scalar + 2 end shuffles.
__global__ __launch_bounds__(256) void attn_mfma_kernel(const short* __restrict__ Q,
                                                        const short* __restrict__ Qt,
                                                        float* __restrict__ Opart,
                                                        float* __restrict__ Lpart) {
  __shared__ short Ks[64 * 64];      // K[key][d]
  __shared__ short Vt[64 * 64];      // V^T[d][key]
  __shared__ short Pw[4 * 16 * 64];  // per-wave P[qrow][key]
  const int h = blockIdx.y;
  const int q0 = blockIdx.x * 64;
  const int kt0 = blockIdx.z * 16;   // 16 K-tiles per split
  const int tid = threadIdx.x;
  const int lane = tid & 63;
  const int wv = tid >> 6;
  const int l15 = lane & 15;
  const int quad = lane >> 4;
  const short* Qh = Q + (size_t)h * (BS_TOK * HD);
  const short* Qth = Qt + (size_t)h * (HD * BS_TOK);
  short* myP = Pw + wv * 16 * 64;

  bf16x8 qf[2];
  {
    const short* qp = Qh + (size_t)(q0 + wv * 16 + l15) * HD + quad * 8;
    qf[0] = *(const bf16x8*)(qp);
    qf[1] = *(const bf16x8*)(qp + 32);
  }

  f32x4 o[4];
  float lpl = 0.f;  // denominator partial for qrow = l15
#pragma unroll
  for (int r = 0; r < 4; ++r) o[r] = (f32x4){0.f, 0.f, 0.f, 0.f};

  // 2+2 b128 chunks per thread per tile (512 chunks per 8KB tile, 256 thr)
  bf16x8 kreg[2], vreg[2];
#pragma unroll
  for (int i = 0; i < 2; ++i) {
    int c = i * 256 + tid;
    kreg[i] = *(const bf16x8*)(Qh + kt0 * 4096 + c * 8);
    vreg[i] = *(const bf16x8*)(Qth + (c >> 3) * BS_TOK + kt0 * 64 + (c & 7) * 8);
  }

  for (int kt = 0; kt < 16; ++kt) {
    __syncthreads();
#pragma unroll
    for (int i = 0; i < 2; ++i) {
      int c = i * 256 + tid, row = c >> 3, g = c & 7;
      *(bf16x8*)&Ks[row * 64 + ((g ^ (row & 7)) << 3)] = kreg[i];
      *(bf16x8*)&Vt[row * 64 + ((g ^ (row & 7)) << 3)] = vreg[i];
    }
    __syncthreads();
    if (kt < 15) {
      int gt = kt0 + kt + 1;
#pragma unroll
      for (int i = 0; i < 2; ++i) {
        int c = i * 256 + tid;
        kreg[i] = *(const bf16x8*)(Qh + gt * 4096 + c * 8);
        vreg[i] = *(const bf16x8*)(Qth + (c >> 3) * BS_TOK + gt * 64 + (c & 7) * 8);
      }
    }

    // S^T = K Q^T  (4 key-tiles of 16); lane: qrow=l15, key=ct*16+quad*4+r
    f32x4 s[4];
#pragma unroll
    for (int ct = 0; ct < 4; ++ct) {
      f32x4 acc = (f32x4){0.f, 0.f, 0.f, 0.f};
#pragma unroll
      for (int ks = 0; ks < 2; ++ks) {
        int row = ct * 16 + l15;  // key row of Ks = A-operand
        int c = ks * 4 + quad;
        bf16x8 kf = *(const bf16x8*)(&Ks[row * 64 + ((c ^ (row & 7)) << 3)]);
        acc = MFMA16(kf, qf[ks], acc);
      }
      s[ct] = acc;
    }

    // no-max softmax: p = exp(s/8); b64 P writes (4 consecutive keys)
#pragma unroll
    for (int ct = 0; ct < 4; ++ct) {
      bf16x4 pv4;
#pragma unroll
      for (int r = 0; r < 4; ++r) {
        float p = __expf(s[ct][r] * 0.125f);
        lpl += p;
        pv4[r] = f2bf(p);
      }
      int g = 2 * ct + (quad >> 1);
      *(bf16x4*)&myP[l15 * 64 + ((g ^ (l15 & 7)) << 3) + ((quad & 1) << 2)] = pv4;
    }

    // O += P V  (wave-local myP; in-wave lgkmcnt ordering, no barrier)
#pragma unroll
    for (int ks = 0; ks < 2; ++ks) {
      int c = ks * 4 + quad;
      bf16x8 pf = *(const bf16x8*)(&myP[l15 * 64 + ((c ^ (l15 & 7)) << 3)]);
#pragma unroll
      for (int dt = 0; dt < 4; ++dt) {
        int row = dt * 16 + l15;
        bf16x8 vf = *(const bf16x8*)(&Vt[row * 64 + ((c ^ (row & 7)) << 3)]);
        o[dt] = MFMA16(pf, vf, o[dt]);
      }
    }
  }

  // reduce denominator across quads (qrow = l15 fixed per lane)
  lpl += __shfl_xor(lpl, 16, 64);
  lpl += __shfl_xor(lpl, 32, 64);

  const int NB = BS_TOK * EMB;
  float* Oh = Opart + (size_t)blockIdx.z * NB + (size_t)h * (BS_TOK * HD);
  float* Lh = Lpart + ((size_t)blockIdx.z * NH + h) * BS_TOK;
  if (quad == 0) Lh[q0 + wv * 16 + l15] = lpl;
#pragma unroll
  for (int r = 0; r < 4; ++r) {
    int qrow = q0 + wv * 16 + quad * 4 + r;
#pragma unroll
    for (int dt = 0; dt < 4; ++dt)
      Oh[(size_t)qrow * HD + dt * 16 + l15] = o[dt][r];
  }
}

// ------------------------------------------------- MH = Wo * combine(Opart)/l
// 128x64 tiles, ksplit=2; combine fused into B staging.
__global__ __launch_bounds__(256) void gemm_out_kernel(const short* __restrict__ Wob,
                                                       const float* __restrict__ Op,
                                                       const float* __restrict__ Lp,
                                                       float* __restrict__ Pp) {
  __shared__ short As[128 * 64];
  __shared__ short Bs[64 * 64];
  const int n0 = blockIdx.x * 64;   // j cols (2048 -> 32)
  const int m0 = blockIdx.y * 128;  // e rows (768 -> 6)
  const int kz = blockIdx.z * 384;  // K half
  const int tid = threadIdx.x;
  const int w = tid >> 6, lane = tid & 63, l15 = lane & 15, quad = lane >> 4;
  f32x4 acc[2][4] = {};
  for (int k0 = 0; k0 < 384; k0 += 64) {
    stage_direct128(Wob, EMB, m0, kz + k0, As, tid);
    stage_trans_comb(Op, Lp, kz + k0, n0, Bs, tid);  // Bs[n][k] <- Z[k][n]
    __syncthreads();
    GEMM_TILE_COMPUTE2(As, Bs, acc);
    __syncthreads();
  }
  float* P = Pp + (size_t)blockIdx.z * (BS_TOK * EMB);
#pragma unroll
  for (int u = 0; u < 2; ++u)
#pragma unroll
    for (int nt = 0; nt < 4; ++nt)
#pragma unroll
      for (int r = 0; r < 4; ++r)
        P[(size_t)(m0 + (w << 5) + (u << 4) + (quad << 2) + r) * BS_TOK + n0 +
          (nt << 4) + l15] = acc[u][nt][r];
}

// ------------------------------------------------- FFN = L1b * fwb^T + fb, 128x64, ksplit=2
__global__ __launch_bounds__(256) void gemm_ffn_kernel(const short* __restrict__ L1b,
                                                       const short* __restrict__ Fwb,
                                                       const float* __restrict__ Fb,
                                                       float* __restrict__ Pp) {
  __shared__ short As[128 * 64];
  __shared__ short Bs[64 * 64];
  const int m0 = blockIdx.x * 128;  // token tile (16)
  const int n0 = blockIdx.y * 64;   // out-feature tile (12)
  const int kz = blockIdx.z * 384;  // K half
  const int tid = threadIdx.x;
  const int w = tid >> 6, lane = tid & 63, l15 = lane & 15, quad = lane >> 4;
  f32x4 acc[2][4] = {};
  for (int k0 = 0; k0 < 384; k0 += 64) {
    stage_direct128(L1b, EMB, m0, kz + k0, As, tid);
    stage_direct_bf16(Fwb, EMB, n0, kz + k0, Bs, tid);  // fw[o][k]
    __syncthreads();
    GEMM_TILE_COMPUTE2(As, Bs, acc);
    __syncthreads();
  }
  float* P = Pp + (size_t)blockIdx.z * (BS_TOK * EMB);
  const bool addb = (blockIdx.z == 0);
#pragma unroll
  for (int nt = 0; nt < 4; ++nt) {
    float bias = addb ? Fb[n0 + (nt << 4) + l15] : 0.0f;
#pragma unroll
    for (int u = 0; u < 2; ++u)
#pragma unroll
      for (int r = 0; r < 4; ++r)
        P[(size_t)(m0 + (w << 5) + (u << 4) + (quad << 2) + r) * EMB + n0 +
          (nt << 4) + l15] = acc[u][nt][r] + bias;
  }
}

// ------------------------------------------------- LN(Xa + P0 + P1) -> fp32 + bf16
__global__ __launch_bounds__(256) void ln_kernel(const float* __restrict__ Xa,
                                                 const float* __restrict__ P,
                                                 const float* __restrict__ g,
                                                 const float* __restrict__ bb,
                                                 float* __restrict__ Out,
                                                 short* __restrict__ Outb) {
  __shared__ float red[4];
  const int NB = BS_TOK * EMB;
  const int t = blockIdx.x;
  const int tid = threadIdx.x;
  float v[3];
  float s = 0.f;
#pragma unroll
  for (int i = 0; i < 3; ++i) {
    int e = tid + i * 256;
    int idx = t * EMB + e;
    v[i] = Xa[idx] + P[idx] + P[idx + NB];
    s += v[i];
  }
#pragma unroll
  for (int o = 32; o > 0; o >>= 1) s += __shfl_xor(s, o, 64);
  if ((tid & 63) == 0) red[tid >> 6] = s;
  __syncthreads();
  float mu = (red[0] + red[1] + red[2] + red[3]) * (1.0f / EMB);
  float q = 0.f;
#pragma unroll
  for (int i = 0; i < 3; ++i) {
    float d = v[i] - mu;
    q += d * d;
  }
#pragma unroll
  for (int o = 32; o > 0; o >>= 1) q += __shfl_xor(q, o, 64);
  __syncthreads();
  if ((tid & 63) == 0) red[tid >> 6] = q;
  __syncthreads();
  float var = (red[0] + red[1] + red[2] + red[3]) * (1.0f / EMB);
  float r = rsqrtf(var + 1e-5f);
#pragma unroll
  for (int i = 0; i < 3; ++i) {
    int e = tid + i * 256;
    float res = (v[i] - mu) * r * g[e] + bb[e];
    Out[t * EMB + e] = res;
    Outb[t * EMB + e] = f2bf(res);
  }
}

extern "C" void kernel_launch(void* const* d_in, const int* in_sizes, int n_in,
                              void* d_out, int out_size, void* d_ws, size_t ws_size,
                              hipStream_t stream) {
  const float* tok = (const float*)d_in[0];
  const float* wq = (const float*)d_in[1];
  const float* wo = (const float*)d_in[2];
  const float* g1 = (const float*)d_in[3];
  const float* b1 = (const float*)d_in[4];
  const float* fw = (const float*)d_in[5];
  const float* fb = (const float*)d_in[6];
  const float* g2 = (const float*)d_in[7];
  const float* b2 = (const float*)d_in[8];
  const int NB = BS_TOK * EMB;  // 1572864 elems
  float* bufA = (float*)d_ws;        // X (residual, fp32)
  float* bufB = bufA + NB;           // gemm partial 0
  float* bufC = bufB + NB;           // gemm partial 1
  float* bufD = bufC + NB;           // L1 fp32
  float* bufE = bufD + NB;           // attn O partial 0
  float* bufF = bufE + NB;           // attn O partial 1 (contiguous after E)
  short* XbA = (short*)(bufF + NB);  // bf16 of current X
  short* L1b = XbA + NB;             // bf16 of L1
  short* Qbf = L1b + NB;             // Q bf16 [H][2048][64]
  short* Qtb = Qbf + NB;             // Qt bf16 [H][64][2048]
  short* wqTb = Qtb + NB;            // wqT bf16 [L][H][64][768]
  short* wob = wqTb + WQN;           // wo bf16 [L][768][768]
  short* fwb = wob + WQN;            // fw bf16 [L][768][768]
  float* Lpart = (float*)(fwb + WQN);  // [2][H][2048]

  cvt_weights_kernel<<<dim3(WQN / (256 * 8), 2), 256, 0, stream>>>(wo, fw, wob, fwb);
  wq_trans_kernel<<<dim3(12, 12 * NH), 256, 0, stream>>>(wq, wqTb);
  pe_add_kernel<<<NB / 256, 256, 0, stream>>>(tok, bufA, XbA);
  for (int it = 0; it < 13; ++it) {
    int l = (it == 0) ? 0 : it - 1;  // layer 0 applied twice (faithful)
    gemm_q_kernel<<<dim3(32, NH), 256, 0, stream>>>(
        XbA, wqTb + (size_t)l * (NH * HD * EMB), Qbf, Qtb);
    attn_mfma_kernel<<<dim3(32, NH, 2), 256, 0, stream>>>(Qbf, Qtb, bufE, Lpart);
    gemm_out_kernel<<<dim3(32, 6, 2), 256, 0, stream>>>(
        wob + (size_t)l * (EMB * EMB), bufE, Lpart, bufB);
    ln_kernel<<<BS_TOK, 256, 0, stream>>>(bufA, bufB, g1 + l * EMB, b1 + l * EMB,
                                          bufD, L1b);
    gemm_ffn_kernel<<<dim3(16, 12, 2), 256, 0, stream>>>(
        L1b, fwb + (size_t)l * (EMB * EMB), fb + l * EMB, bufB);
    float* ln2_dst = (it == 12) ? (float*)d_out : bufA;
    ln_kernel<<<BS_TOK, 256, 0, stream>>>(bufD, bufB, g2 + l * EMB, b2 + l * EMB,
                                          ln2_dst, XbA);
  }
}